// Round 9
// baseline (264.574 us; speedup 1.0000x reference)
//
#include <hip/hip_runtime.h>
#include <math.h>

// ---------------------------------------------------------------------------
// GCN, atomic-free aggregation via per-call CSR (bucket by dst):
//   deg count (dst-partitioned) -> block scan(+dinv) -> add_offsets (fused
//   bsum scan) -> fill (dst-partitioned, XCD-local, u16)          [once]
//   gemm1:  G1 = (x@W1)*dinv               (fp32 in, bf16 out, W in LDS)
//   aggemv<64>: y1 = relu(dinv*(G1self+gather)+b1); G2 = (y1@W2)*dinv  [fused]
//   aggemv<40>: y2 = relu(...b2);           G3 = (y2@W3)*dinv          [fused]
//   agg40_lsm:  y3 = relu(...b3);           out = log_softmax(y3)
// Fusion rationale: r7 vs r8 isolate GEMM dispatch cost at ~40us each (hidden
// below the 43us harness-fill top-5 cutoff). After the agg butterfly
// allreduce every lane holds the full fp32 output row (8 cols/lane), so the
// next layer's GEMM is a wave-local gemv: 64 shfl + 64 ds_read_b32 + 64 FMA
// per node, W staged once per block in LDS. Kills 2 GEMM dispatches + 25.6MB.
// agg gather: lane=(grp<<3)|sub, uint4 loads (8 bf16), 8 edge rows/instr.
// cidx u16 (N_NODES=50000<65536). r7 lesson: avoid low-occupancy reg tiles.
// NOTE: no hipMemsetAsync — rocclr fillBuffer took 45.9us for 195KB in-graph.
// ---------------------------------------------------------------------------

#define DF 64
#define TB 256
#define NPART 8

__device__ __forceinline__ unsigned short f2bf(float f) {
    union { float f; unsigned u; } c; c.f = f;
    unsigned u = c.u;
    return (unsigned short)((u + 0x7fffu + ((u >> 16) & 1u)) >> 16);   // RNE
}
__device__ __forceinline__ float bf2f(unsigned short h) {
    union { unsigned u; float f; } c; c.u = ((unsigned)h) << 16;
    return c.f;
}
__device__ __forceinline__ void acc_bf16x8(uint4 v, float* a) {
    a[0] += bf2f((unsigned short)(v.x & 0xffffu));
    a[1] += bf2f((unsigned short)(v.x >> 16));
    a[2] += bf2f((unsigned short)(v.y & 0xffffu));
    a[3] += bf2f((unsigned short)(v.y >> 16));
    a[4] += bf2f((unsigned short)(v.z & 0xffffu));
    a[5] += bf2f((unsigned short)(v.z >> 16));
    a[6] += bf2f((unsigned short)(v.w & 0xffffu));
    a[7] += bf2f((unsigned short)(v.w >> 16));
}
__device__ __forceinline__ void acc_bf16x4(uint2 v, float* a) {
    a[0] += bf2f((unsigned short)(v.x & 0xffffu));
    a[1] += bf2f((unsigned short)(v.x >> 16));
    a[2] += bf2f((unsigned short)(v.y & 0xffffu));
    a[3] += bf2f((unsigned short)(v.y >> 16));
}

__global__ void zero_int_kernel(int* __restrict__ p, int n) {
    int i = blockIdx.x * blockDim.x + threadIdx.x;
    if (i < n) p[i] = 0;
}

__global__ void count_deg_part_kernel(const int* __restrict__ dst, int* __restrict__ deg,
                                      int e, int psize) {
    const int p   = blockIdx.x & (NPART - 1);
    const int sl  = blockIdx.x / NPART;
    const int nsl = gridDim.x / NPART;
    const int lo = p * psize, hi = lo + psize;
    for (int i = sl * TB + threadIdx.x; i < e; i += nsl * TB) {
        int d = dst[i];
        if (d >= lo && d < hi) atomicAdd(&deg[d], 1);
    }
}

// per-block exclusive scan of deg -> ex (partial), block totals -> bsum; also dinv
__global__ void scan_block_kernel(const int* __restrict__ deg, int* __restrict__ ex,
                                  int* __restrict__ bsum, float* __restrict__ dinv, int n) {
    __shared__ int s[TB];
    const int t = threadIdx.x;
    const int i = blockIdx.x * TB + t;
    int v = (i < n) ? deg[i] : 0;
    if (i < n) dinv[i] = rsqrtf((float)(v + 1));   // +1 self-loop
    s[t] = v; __syncthreads();
#pragma unroll
    for (int o = 1; o < TB; o <<= 1) {
        int u = (t >= o) ? s[t - o] : 0;
        __syncthreads();
        s[t] += u;
        __syncthreads();
    }
    if (i < n) ex[i] = s[t] - v;
    if (t == TB - 1) bsum[blockIdx.x] = s[TB - 1];
}

// each block redundantly scans bsum (nb <= 256) in LDS, then offsets its slice
__global__ void add_offsets_kernel(int* __restrict__ ex, const int* __restrict__ bsum,
                                   int* __restrict__ cursor, int n, int nb) {
    __shared__ int s[TB];
    const int t = threadIdx.x;
    int v = (t < nb) ? bsum[t] : 0;
    s[t] = v; __syncthreads();
#pragma unroll
    for (int o = 1; o < TB; o <<= 1) {
        int u = (t >= o) ? s[t - o] : 0;
        __syncthreads();
        s[t] += u;
        __syncthreads();
    }
    const int boff = (blockIdx.x > 0) ? s[blockIdx.x - 1] : 0;
    const int i = blockIdx.x * TB + t;
    if (i < n) {
        int r = ex[i] + boff;
        ex[i] = r;
        cursor[i] = r;
    }
}

__global__ void fill_csr_part_kernel(const int* __restrict__ src, const int* __restrict__ dst,
                                     int* __restrict__ cursor,
                                     unsigned short* __restrict__ cidx, int e, int psize) {
    const int p   = blockIdx.x & (NPART - 1);
    const int sl  = blockIdx.x / NPART;
    const int nsl = gridDim.x / NPART;
    const int lo = p * psize, hi = lo + psize;
    for (int i = sl * TB + threadIdx.x; i < e; i += nsl * TB) {
        int d = dst[i];
        if (d >= lo && d < hi) {
            int pos = atomicAdd(&cursor[d], 1);
            cidx[pos] = (unsigned short)src[i];
        }
    }
}

// G[M x 64](bf16) = (X[M x 64] @ W[64 x 64]) * dinv[row].  Layer 1 only.
// Block (16,16): 16 rows/block, each thread 1 row x 4 cols (float4 W reads).
__global__ __launch_bounds__(256) void gemm_kernel(const float* __restrict__ X,
                                                   const float* __restrict__ W,
                                                   const float* __restrict__ dinv,
                                                   unsigned short* __restrict__ G, int M) {
    __shared__ float Ws[64 * 64];
    __shared__ float Xs[16][65];
    const int tx = threadIdx.x;            // 0..15 col group
    const int ty = threadIdx.y;            // 0..15 row
    const int tid = ty * 16 + tx;
    for (int i = tid; i < 16 * 64; i += 256)
        ((float4*)Ws)[i] = ((const float4*)W)[i];
    const int row0 = blockIdx.x * 16;
    {   // stage 16 rows of X: 256 threads x float4
        int r = tid / 16, c4 = tid % 16;
        float4 v = (row0 + r < M) ? ((const float4*)(X + (size_t)(row0 + r) * 64))[c4]
                                  : make_float4(0.f, 0.f, 0.f, 0.f);
        Xs[r][c4 * 4 + 0] = v.x; Xs[r][c4 * 4 + 1] = v.y;
        Xs[r][c4 * 4 + 2] = v.z; Xs[r][c4 * 4 + 3] = v.w;
    }
    __syncthreads();
    const int row = row0 + ty;
    if (row < M) {
        float a0 = 0.f, a1 = 0.f, a2 = 0.f, a3 = 0.f;
#pragma unroll
        for (int k = 0; k < 64; ++k) {
            float xk = Xs[ty][k];
            float4 w = ((const float4*)(Ws + (size_t)k * 64))[tx];
            a0 += xk * w.x; a1 += xk * w.y; a2 += xk * w.z; a3 += xk * w.w;
        }
        float di = dinv[row];
        ushort4 o;
        o.x = f2bf(a0 * di); o.y = f2bf(a1 * di);
        o.z = f2bf(a2 * di); o.w = f2bf(a3 * di);
        *((ushort4*)(G + (size_t)row * 64 + tx * 4)) = o;
    }
}

// Fused: NC_in=64 aggregation + next-layer gemv (NCO = 64 or 40).
// One wave per node; lane=(grp<<3)|sub. Gather uint4 (8 bf16), 8 rows/instr;
// butterfly allreduce -> ALL lanes hold y[sub*8..sub*8+7] (fp32, relu'd).
// Then Gout[node, lane] = (sum_k y[k]*Wn[k][lane]) * dinv[node], Wn in LDS.
template <int NCO>
__global__ __launch_bounds__(256) void aggemv_kernel(
        const unsigned short* __restrict__ G,
        const int* __restrict__ rowptr, const int* __restrict__ deg,
        const unsigned short* __restrict__ cidx,
        const float* __restrict__ dinv, const float* __restrict__ b,
        const float* __restrict__ Wn,
        unsigned short* __restrict__ Gout, int M) {
    __shared__ float Ws[64 * NCO];
    const int tid = threadIdx.x;
    for (int i = tid; i < 16 * NCO; i += 256)       // 64*NCO/4 float4s
        ((float4*)Ws)[i] = ((const float4*)Wn)[i];
    __syncthreads();

    const int lane = tid & 63;
    const int node = blockIdx.x * 4 + (tid >> 6);
    if (node >= M) return;
    const int grp = lane >> 3;                 // 0..7 edge slot
    const int sub = lane & 7;                  // 0..7 col octet
    const int start = rowptr[node];
    const int cnt = deg[node];

    float a[8] = {0.f, 0.f, 0.f, 0.f, 0.f, 0.f, 0.f, 0.f};
    float c[8] = {0.f, 0.f, 0.f, 0.f, 0.f, 0.f, 0.f, 0.f};

    for (int base = 0; base < cnt; base += 64) {
        const int nthis = min(64, cnt - base);
        int myidx = (lane < nthis) ? (int)cidx[start + base + lane] : 0;
        int j = 0;
        for (; j + 16 <= nthis; j += 16) {
            int s0 = __shfl(myidx, j + grp, 64);
            int s1 = __shfl(myidx, j + 8 + grp, 64);
            uint4 v0 = *(const uint4*)(G + (size_t)s0 * 64 + sub * 8);
            uint4 v1 = *(const uint4*)(G + (size_t)s1 * 64 + sub * 8);
            acc_bf16x8(v0, a);
            acc_bf16x8(v1, c);
        }
        if (j + 8 <= nthis) {
            int s0 = __shfl(myidx, j + grp, 64);
            uint4 v0 = *(const uint4*)(G + (size_t)s0 * 64 + sub * 8);
            acc_bf16x8(v0, a);
            j += 8;
        }
        const int rem = nthis - j;             // 0..7
        if (grp < rem) {
            int s0 = __shfl(myidx, j + grp, 64);
            uint4 v0 = *(const uint4*)(G + (size_t)s0 * 64 + sub * 8);
            acc_bf16x8(v0, c);
        }
    }
#pragma unroll
    for (int k = 0; k < 8; ++k) a[k] += c[k];
#pragma unroll
    for (int k = 0; k < 8; ++k) {              // butterfly allreduce
        a[k] += __shfl_xor(a[k], 8, 64);
        a[k] += __shfl_xor(a[k], 16, 64);
        a[k] += __shfl_xor(a[k], 32, 64);
    }
    // epilogue on ALL lanes: y = relu(dinv*(self+agg) + b) for cols sub*8..+7
    uint4 sv = *(const uint4*)(G + (size_t)node * 64 + sub * 8);
    float4 b0 = *(const float4*)(b + sub * 8);
    float4 b1 = *(const float4*)(b + sub * 8 + 4);
    const float di = dinv[node];
    float v[8];
    v[0] = fmaxf((a[0] + bf2f((unsigned short)(sv.x & 0xffffu))) * di + b0.x, 0.f);
    v[1] = fmaxf((a[1] + bf2f((unsigned short)(sv.x >> 16)))     * di + b0.y, 0.f);
    v[2] = fmaxf((a[2] + bf2f((unsigned short)(sv.y & 0xffffu))) * di + b0.z, 0.f);
    v[3] = fmaxf((a[3] + bf2f((unsigned short)(sv.y >> 16)))     * di + b0.w, 0.f);
    v[4] = fmaxf((a[4] + bf2f((unsigned short)(sv.z & 0xffffu))) * di + b1.x, 0.f);
    v[5] = fmaxf((a[5] + bf2f((unsigned short)(sv.z >> 16)))     * di + b1.y, 0.f);
    v[6] = fmaxf((a[6] + bf2f((unsigned short)(sv.w & 0xffffu))) * di + b1.z, 0.f);
    v[7] = fmaxf((a[7] + bf2f((unsigned short)(sv.w >> 16)))     * di + b1.w, 0.f);

    // gemv: Gout[node, lane] = (sum_k y[k] * Ws[k*NCO + lane]) * dinv
    float acc0 = 0.f, acc1 = 0.f;
#pragma unroll
    for (int s = 0; s < 8; s += 2) {
#pragma unroll
        for (int j = 0; j < 8; ++j) {
            float y0 = __shfl(v[j], s, 64);        // y[s*8+j]   (lane s holds it)
            float y1 = __shfl(v[j], s + 1, 64);    // y[(s+1)*8+j]
            if (lane < NCO) {
                acc0 += y0 * Ws[(s * 8 + j) * NCO + lane];
                acc1 += y1 * Ws[((s + 1) * 8 + j) * NCO + lane];
            }
        }
    }
    if (lane < NCO)
        Gout[(size_t)node * NCO + lane] = f2bf((acc0 + acc1) * di);
}

// NC=40 aggregation + fused log_softmax. lane = grp(2b)*16 + sub(4b);
// lane owns cols [sub*4, sub*4+4); 4 edge rows per instruction.
__global__ void agg40_lsm_kernel(const unsigned short* __restrict__ G,
                                 const int* __restrict__ rowptr, const int* __restrict__ deg,
                                 const unsigned short* __restrict__ cidx,
                                 const float* __restrict__ dinv, const float* __restrict__ b,
                                 float* __restrict__ Y, int M) {
    constexpr int NC = 40;
    constexpr int NQ = 10;
    const int lane = threadIdx.x & 63;
    const int node = blockIdx.x * 4 + (threadIdx.x >> 6);
    if (node >= M) return;
    const int grp = lane >> 4;                 // 0..3
    const int sub = lane & 15;                 // 0..15
    const bool act = (sub < NQ);
    const int start = rowptr[node];
    const int cnt = deg[node];

    float a[4] = {0.f, 0.f, 0.f, 0.f};
    float c[4] = {0.f, 0.f, 0.f, 0.f};

    for (int base = 0; base < cnt; base += 64) {
        const int nthis = min(64, cnt - base);
        int myidx = (lane < nthis) ? (int)cidx[start + base + lane] : 0;
        int j = 0;
        for (; j + 8 <= nthis; j += 8) {
            int s0 = __shfl(myidx, j + grp, 64);
            int s1 = __shfl(myidx, j + 4 + grp, 64);
            if (act) {
                uint2 v0 = *(const uint2*)(G + (size_t)s0 * NC + sub * 4);
                uint2 v1 = *(const uint2*)(G + (size_t)s1 * NC + sub * 4);
                acc_bf16x4(v0, a);
                acc_bf16x4(v1, c);
            }
        }
        if (j + 4 <= nthis) {
            int s0 = __shfl(myidx, j + grp, 64);
            if (act) {
                uint2 v0 = *(const uint2*)(G + (size_t)s0 * NC + sub * 4);
                acc_bf16x4(v0, a);
            }
            j += 4;
        }
        const int rem = nthis - j;             // 0..3
        if (grp < rem) {
            int s0 = __shfl(myidx, j + grp, 64);
            if (act) {
                uint2 v0 = *(const uint2*)(G + (size_t)s0 * NC + sub * 4);
                acc_bf16x4(v0, c);
            }
        }
    }
#pragma unroll
    for (int k = 0; k < 4; ++k) a[k] += c[k];
#pragma unroll
    for (int k = 0; k < 4; ++k) {
        a[k] += __shfl_xor(a[k], 16, 64);
        a[k] += __shfl_xor(a[k], 32, 64);
    }
    float v[4];
    {
        float self[4] = {0.f, 0.f, 0.f, 0.f};
        float4 bb = make_float4(0.f, 0.f, 0.f, 0.f);
        if (act) {
            uint2 sv = *(const uint2*)(G + (size_t)node * NC + sub * 4);
            self[0] = bf2f((unsigned short)(sv.x & 0xffffu));
            self[1] = bf2f((unsigned short)(sv.x >> 16));
            self[2] = bf2f((unsigned short)(sv.y & 0xffffu));
            self[3] = bf2f((unsigned short)(sv.y >> 16));
            bb = *(const float4*)(b + sub * 4);
        }
        const float di = dinv[node];
        v[0] = fmaxf((a[0] + self[0]) * di + bb.x, 0.f);
        v[1] = fmaxf((a[1] + self[1]) * di + bb.y, 0.f);
        v[2] = fmaxf((a[2] + self[2]) * di + bb.z, 0.f);
        v[3] = fmaxf((a[3] + self[3]) * di + bb.w, 0.f);
    }
    float m = act ? fmaxf(fmaxf(v[0], v[1]), fmaxf(v[2], v[3])) : -INFINITY;
#pragma unroll
    for (int o = 1; o < 16; o <<= 1) m = fmaxf(m, __shfl_xor(m, o, 64));
    float es = act ? (expf(v[0] - m) + expf(v[1] - m) + expf(v[2] - m) + expf(v[3] - m)) : 0.f;
#pragma unroll
    for (int o = 1; o < 16; o <<= 1) es += __shfl_xor(es, o, 64);
    const float ls = logf(es);
    if (act && grp == 0) {
        *((float4*)(Y + (size_t)node * NC + sub * 4)) =
            make_float4(v[0] - m - ls, v[1] - m - ls, v[2] - m - ls, v[3] - m - ls);
    }
}

extern "C" void kernel_launch(void* const* d_in, const int* in_sizes, int n_in,
                              void* d_out, int out_size, void* d_ws, size_t ws_size,
                              hipStream_t stream) {
    const float* x  = (const float*)d_in[0];
    const int*   ei = (const int*)d_in[1];        // [2, E] int32
    const float* W1 = (const float*)d_in[2];
    const float* b1 = (const float*)d_in[3];
    const float* W2 = (const float*)d_in[4];
    const float* b2 = (const float*)d_in[5];
    const float* W3 = (const float*)d_in[6];
    const float* b3 = (const float*)d_in[7];
    float* out = (float*)d_out;

    const int M  = in_sizes[0] / DF;              // 50000
    const int E  = in_sizes[1] / 2;               // 800000
    (void)ws_size; (void)n_in; (void)out_size;

    const int* src = ei;
    const int* dst = ei + E;

    const size_t Ma = ((size_t)M + 63) & ~63ull;
    const size_t Ea = ((size_t)E + 63) & ~63ull;

    // workspace layout
    int* deg    = (int*)d_ws;                            // Ma
    int* rowptr = deg + Ma;                              // Ma
    int* cursor = rowptr + Ma;                           // Ma
    int* bsum   = cursor + Ma;                           // 256
    unsigned short* cidx = (unsigned short*)(bsum + 256);        // Ea (u16)
    float* dinv = (float*)(cidx + Ea);                   // Ma
    unsigned short* G0 = (unsigned short*)(dinv + Ma);           // Ma*64 (bf16)
    unsigned short* G1 = G0 + Ma * DF;                   // Ma*64 (bf16)

    const int gN = (M + TB - 1) / TB;
    const int nb = gN;                   // scan blocks (196 <= 256)
    const int psize = (M + NPART - 1) / NPART;
    const int partGrd = NPART * 96;      // 8 partitions x 96 slices

    // --- CSR build + dinv (once, reused by all 3 layers) ---
    zero_int_kernel<<<gN, TB, 0, stream>>>(deg, M);
    count_deg_part_kernel<<<partGrd, TB, 0, stream>>>(dst, deg, E, psize);
    scan_block_kernel<<<nb, TB, 0, stream>>>(deg, rowptr, bsum, dinv, M);
    add_offsets_kernel<<<nb, TB, 0, stream>>>(rowptr, bsum, cursor, M, nb);
    fill_csr_part_kernel<<<partGrd, TB, 0, stream>>>(src, dst, cursor, cidx, E, psize);

    const dim3 gemmBlk(16, 16);
    const int  gemmGrd = (M + 15) / 16;
    const int  aggGrd  = (M + 3) / 4;

    // layer-1 dense transform (only standalone GEMM left)
    gemm_kernel<<<gemmGrd, gemmBlk, 0, stream>>>(x, W1, dinv, G0, M);
    // layer-1 aggregate + layer-2 transform (fused)
    aggemv_kernel<64><<<aggGrd, TB, 0, stream>>>(G0, rowptr, deg, cidx, dinv, b1, W2, G1, M);
    // layer-2 aggregate + layer-3 transform (fused)
    aggemv_kernel<40><<<aggGrd, TB, 0, stream>>>(G1, rowptr, deg, cidx, dinv, b2, W3, G0, M);
    // layer-3 aggregate + log_softmax
    agg40_lsm_kernel<<<aggGrd, TB, 0, stream>>>(G0, rowptr, deg, cidx, dinv, b3, out, M);
}

// Round 10
// 196.432 us; speedup vs baseline: 1.3469x; 1.3469x over previous
//
#include <hip/hip_runtime.h>
#include <math.h>

// ---------------------------------------------------------------------------
// GCN, atomic-free aggregation via per-call CSR (bucket by dst):
//   deg count (dst-partitioned) -> block scan(+dinv) -> add_offsets (fused
//   bsum scan) -> fill (dst-partitioned, XCD-local, u16)          [once]
//   per layer: G = (X@W)*dinv[row]   (MFMA 16x16x32 bf16, W frags in VGPRs,
//              ZERO LDS — r2..r8's W-in-LDS GEMM was LDS-pipe-bound at ~40us;
//              r9's shfl+LDS gemv fusion was worse, 74us. Register operands.)
//              y[i] = relu( dinv[i]*(G[i] + sum_{e: dst=i} G[src_e]) + b )
//   layers 1-2 emit bf16 activations; layer 3 fuses log_softmax (fp32 out).
// agg64: one wave per node; lane=(grp<<3)|sub, uint4 loads (8 bf16 cols),
//   8 edge rows per instruction; butterfly shfl_xor(8|16|32) merge.
// agg40: 16-lane rows (uint2), 4 edge rows/instr, fused log_softmax.
// MFMA layouts (guide-verified m89/m97): A lane(m=l&15,g=l>>4)=A[m][g*8+j];
//   B lane(n=l&15,g)=B[g*8+j][n]; C/D lane: col=l&15, row=(l>>4)*4+reg.
// cidx u16 (N_NODES=50000<65536).
// NOTE: no hipMemsetAsync — rocclr fillBuffer took 45.9us for 195KB in-graph.
// ---------------------------------------------------------------------------

#define DF 64
#define TB 256
#define NPART 8

typedef __attribute__((ext_vector_type(8))) short bf16x8;
typedef __attribute__((ext_vector_type(4))) float f32x4;

__device__ __forceinline__ unsigned short f2bf(float f) {
    union { float f; unsigned u; } c; c.f = f;
    unsigned u = c.u;
    return (unsigned short)((u + 0x7fffu + ((u >> 16) & 1u)) >> 16);   // RNE
}
__device__ __forceinline__ float bf2f(unsigned short h) {
    union { unsigned u; float f; } c; c.u = ((unsigned)h) << 16;
    return c.f;
}
__device__ __forceinline__ void acc_bf16x8(uint4 v, float* a) {
    a[0] += bf2f((unsigned short)(v.x & 0xffffu));
    a[1] += bf2f((unsigned short)(v.x >> 16));
    a[2] += bf2f((unsigned short)(v.y & 0xffffu));
    a[3] += bf2f((unsigned short)(v.y >> 16));
    a[4] += bf2f((unsigned short)(v.z & 0xffffu));
    a[5] += bf2f((unsigned short)(v.z >> 16));
    a[6] += bf2f((unsigned short)(v.w & 0xffffu));
    a[7] += bf2f((unsigned short)(v.w >> 16));
}
__device__ __forceinline__ void acc_bf16x4(uint2 v, float* a) {
    a[0] += bf2f((unsigned short)(v.x & 0xffffu));
    a[1] += bf2f((unsigned short)(v.x >> 16));
    a[2] += bf2f((unsigned short)(v.y & 0xffffu));
    a[3] += bf2f((unsigned short)(v.y >> 16));
}

__global__ void zero_int_kernel(int* __restrict__ p, int n) {
    int i = blockIdx.x * blockDim.x + threadIdx.x;
    if (i < n) p[i] = 0;
}

__global__ void count_deg_part_kernel(const int* __restrict__ dst, int* __restrict__ deg,
                                      int e, int psize) {
    const int p   = blockIdx.x & (NPART - 1);
    const int sl  = blockIdx.x / NPART;
    const int nsl = gridDim.x / NPART;
    const int lo = p * psize, hi = lo + psize;
    for (int i = sl * TB + threadIdx.x; i < e; i += nsl * TB) {
        int d = dst[i];
        if (d >= lo && d < hi) atomicAdd(&deg[d], 1);
    }
}

// per-block exclusive scan of deg -> ex (partial), block totals -> bsum; also dinv
__global__ void scan_block_kernel(const int* __restrict__ deg, int* __restrict__ ex,
                                  int* __restrict__ bsum, float* __restrict__ dinv, int n) {
    __shared__ int s[TB];
    const int t = threadIdx.x;
    const int i = blockIdx.x * TB + t;
    int v = (i < n) ? deg[i] : 0;
    if (i < n) dinv[i] = rsqrtf((float)(v + 1));   // +1 self-loop
    s[t] = v; __syncthreads();
#pragma unroll
    for (int o = 1; o < TB; o <<= 1) {
        int u = (t >= o) ? s[t - o] : 0;
        __syncthreads();
        s[t] += u;
        __syncthreads();
    }
    if (i < n) ex[i] = s[t] - v;
    if (t == TB - 1) bsum[blockIdx.x] = s[TB - 1];
}

// each block redundantly scans bsum (nb <= 256) in LDS, then offsets its slice
__global__ void add_offsets_kernel(int* __restrict__ ex, const int* __restrict__ bsum,
                                   int* __restrict__ cursor, int n, int nb) {
    __shared__ int s[TB];
    const int t = threadIdx.x;
    int v = (t < nb) ? bsum[t] : 0;
    s[t] = v; __syncthreads();
#pragma unroll
    for (int o = 1; o < TB; o <<= 1) {
        int u = (t >= o) ? s[t - o] : 0;
        __syncthreads();
        s[t] += u;
        __syncthreads();
    }
    const int boff = (blockIdx.x > 0) ? s[blockIdx.x - 1] : 0;
    const int i = blockIdx.x * TB + t;
    if (i < n) {
        int r = ex[i] + boff;
        ex[i] = r;
        cursor[i] = r;
    }
}

__global__ void fill_csr_part_kernel(const int* __restrict__ src, const int* __restrict__ dst,
                                     int* __restrict__ cursor,
                                     unsigned short* __restrict__ cidx, int e, int psize) {
    const int p   = blockIdx.x & (NPART - 1);
    const int sl  = blockIdx.x / NPART;
    const int nsl = gridDim.x / NPART;
    const int lo = p * psize, hi = lo + psize;
    for (int i = sl * TB + threadIdx.x; i < e; i += nsl * TB) {
        int d = dst[i];
        if (d >= lo && d < hi) {
            int pos = atomicAdd(&cursor[d], 1);
            cidx[pos] = (unsigned short)src[i];
        }
    }
}

// G[M x NCO](bf16) = (X[M x 64] @ W[64 x NCO]) * dinv[row], via MFMA 16x16x32.
// One wave per 16-row tile; W fragments in VGPRs (loaded once per wave);
// no LDS at all. TIN = float (layer 1) or unsigned short bf16 (layers 2,3).
template <int NCO, typename TIN>
__global__ __launch_bounds__(256) void gemm_mfma_kernel(
        const TIN* __restrict__ X, const float* __restrict__ W,
        const float* __restrict__ dinv, unsigned short* __restrict__ G, int M) {
    constexpr int NCT = (NCO + 15) / 16;       // col tiles: 4 (64) or 3 (40)
    const int lane = threadIdx.x & 63;
    const int wid  = threadIdx.x >> 6;         // 0..3
    const int t    = blockIdx.x * 4 + wid;     // row-tile index
    const int nt   = (M + 15) >> 4;
    if (t >= nt) return;
    const int n = lane & 15;                   // A row (m) / C,D col
    const int g = lane >> 4;                   // k-group / C,D row-group

    // B fragments: bf[ct][ks][j] = W[ks*32 + g*8 + j][ct*16 + n]  (bf16)
    bf16x8 bf[NCT][2];
#pragma unroll
    for (int ct = 0; ct < NCT; ++ct) {
        const int c = ct * 16 + n;
#pragma unroll
        for (int ks = 0; ks < 2; ++ks) {
#pragma unroll
            for (int j = 0; j < 8; ++j) {
                const int k = ks * 32 + g * 8 + j;
                float w = (c < NCO) ? W[k * NCO + c] : 0.f;
                bf[ct][ks][j] = (short)f2bf(w);
            }
        }
    }

    // A fragments: af[ks][j] = X[t*16 + n][ks*32 + g*8 + j]
    const int row_a = t * 16 + n;
    const int ra = (row_a < M) ? row_a : (M - 1);
    bf16x8 af[2];
    if (sizeof(TIN) == 4) {
        const float* Xf = (const float*)X;
#pragma unroll
        for (int ks = 0; ks < 2; ++ks) {
            float4 p0 = *(const float4*)(Xf + (size_t)ra * 64 + ks * 32 + g * 8);
            float4 p1 = *(const float4*)(Xf + (size_t)ra * 64 + ks * 32 + g * 8 + 4);
            af[ks][0] = (short)f2bf(p0.x); af[ks][1] = (short)f2bf(p0.y);
            af[ks][2] = (short)f2bf(p0.z); af[ks][3] = (short)f2bf(p0.w);
            af[ks][4] = (short)f2bf(p1.x); af[ks][5] = (short)f2bf(p1.y);
            af[ks][6] = (short)f2bf(p1.z); af[ks][7] = (short)f2bf(p1.w);
        }
    } else {
        const short* Xh = (const short*)X;
#pragma unroll
        for (int ks = 0; ks < 2; ++ks)
            af[ks] = *(const bf16x8*)(Xh + (size_t)ra * 64 + ks * 32 + g * 8);
    }

    // dinv for the 4 output rows this lane stores (C/D row = g*4 + r)
    const int rbase = t * 16 + g * 4;
    float di[4];
#pragma unroll
    for (int r = 0; r < 4; ++r) {
        int rr = rbase + r;
        di[r] = dinv[(rr < M) ? rr : (M - 1)];
    }

#pragma unroll
    for (int ct = 0; ct < NCT; ++ct) {
        f32x4 acc = {0.f, 0.f, 0.f, 0.f};
        acc = __builtin_amdgcn_mfma_f32_16x16x32_bf16(af[0], bf[ct][0], acc, 0, 0, 0);
        acc = __builtin_amdgcn_mfma_f32_16x16x32_bf16(af[1], bf[ct][1], acc, 0, 0, 0);
        const int col = ct * 16 + n;
#pragma unroll
        for (int r = 0; r < 4; ++r) {
            const int row = rbase + r;
            if (row < M && col < NCO)
                G[(size_t)row * NCO + col] = f2bf(acc[r] * di[r]);
        }
    }
}

// NC=64 aggregation. One wave per node; lane = grp(3b)*8 + sub(3b).
// lane loads uint4 (8 bf16 cols at sub*8); 8 lanes cover a row; 8 edge rows
// per instruction. Merge partials via shfl_xor(8|16|32).
__global__ void agg64_kernel(const unsigned short* __restrict__ G,
                             const int* __restrict__ rowptr, const int* __restrict__ deg,
                             const unsigned short* __restrict__ cidx,
                             const float* __restrict__ dinv, const float* __restrict__ b,
                             unsigned short* __restrict__ Y, int M) {
    const int lane = threadIdx.x & 63;
    const int node = blockIdx.x * 4 + (threadIdx.x >> 6);
    if (node >= M) return;
    const int grp = lane >> 3;                 // 0..7 edge slot
    const int sub = lane & 7;                  // 0..7 col octet
    const int start = rowptr[node];
    const int cnt = deg[node];

    float a[8] = {0.f, 0.f, 0.f, 0.f, 0.f, 0.f, 0.f, 0.f};
    float c[8] = {0.f, 0.f, 0.f, 0.f, 0.f, 0.f, 0.f, 0.f};

    for (int base = 0; base < cnt; base += 64) {
        const int nthis = min(64, cnt - base);
        int myidx = (lane < nthis) ? (int)cidx[start + base + lane] : 0;
        int j = 0;
        for (; j + 16 <= nthis; j += 16) {
            int s0 = __shfl(myidx, j + grp, 64);
            int s1 = __shfl(myidx, j + 8 + grp, 64);
            uint4 v0 = *(const uint4*)(G + (size_t)s0 * 64 + sub * 8);
            uint4 v1 = *(const uint4*)(G + (size_t)s1 * 64 + sub * 8);
            acc_bf16x8(v0, a);
            acc_bf16x8(v1, c);
        }
        if (j + 8 <= nthis) {
            int s0 = __shfl(myidx, j + grp, 64);
            uint4 v0 = *(const uint4*)(G + (size_t)s0 * 64 + sub * 8);
            acc_bf16x8(v0, a);
            j += 8;
        }
        const int rem = nthis - j;             // 0..7
        if (grp < rem) {
            int s0 = __shfl(myidx, j + grp, 64);
            uint4 v0 = *(const uint4*)(G + (size_t)s0 * 64 + sub * 8);
            acc_bf16x8(v0, c);
        }
    }
#pragma unroll
    for (int k = 0; k < 8; ++k) a[k] += c[k];
#pragma unroll
    for (int k = 0; k < 8; ++k) {
        a[k] += __shfl_xor(a[k], 8, 64);
        a[k] += __shfl_xor(a[k], 16, 64);
        a[k] += __shfl_xor(a[k], 32, 64);
    }
    if (grp != 0) return;
    // self term + bias + relu + bf16 store (lanes 0..7)
    uint4 sv = *(const uint4*)(G + (size_t)node * 64 + sub * 8);
    float self[8];
    self[0] = bf2f((unsigned short)(sv.x & 0xffffu)); self[1] = bf2f((unsigned short)(sv.x >> 16));
    self[2] = bf2f((unsigned short)(sv.y & 0xffffu)); self[3] = bf2f((unsigned short)(sv.y >> 16));
    self[4] = bf2f((unsigned short)(sv.z & 0xffffu)); self[5] = bf2f((unsigned short)(sv.z >> 16));
    self[6] = bf2f((unsigned short)(sv.w & 0xffffu)); self[7] = bf2f((unsigned short)(sv.w >> 16));
    float4 b0 = *(const float4*)(b + sub * 8);
    float4 b1 = *(const float4*)(b + sub * 8 + 4);
    const float di = dinv[node];
    float v[8];
    v[0] = fmaxf((a[0] + self[0]) * di + b0.x, 0.f);
    v[1] = fmaxf((a[1] + self[1]) * di + b0.y, 0.f);
    v[2] = fmaxf((a[2] + self[2]) * di + b0.z, 0.f);
    v[3] = fmaxf((a[3] + self[3]) * di + b0.w, 0.f);
    v[4] = fmaxf((a[4] + self[4]) * di + b1.x, 0.f);
    v[5] = fmaxf((a[5] + self[5]) * di + b1.y, 0.f);
    v[6] = fmaxf((a[6] + self[6]) * di + b1.z, 0.f);
    v[7] = fmaxf((a[7] + self[7]) * di + b1.w, 0.f);
    uint4 o;
    o.x = (unsigned)f2bf(v[0]) | ((unsigned)f2bf(v[1]) << 16);
    o.y = (unsigned)f2bf(v[2]) | ((unsigned)f2bf(v[3]) << 16);
    o.z = (unsigned)f2bf(v[4]) | ((unsigned)f2bf(v[5]) << 16);
    o.w = (unsigned)f2bf(v[6]) | ((unsigned)f2bf(v[7]) << 16);
    *((uint4*)(Y + (size_t)node * 64 + sub * 8)) = o;
}

// NC=40 aggregation + fused log_softmax. lane = grp(2b)*16 + sub(4b);
// lane owns cols [sub*4, sub*4+4); 4 edge rows per instruction.
__global__ void agg40_lsm_kernel(const unsigned short* __restrict__ G,
                                 const int* __restrict__ rowptr, const int* __restrict__ deg,
                                 const unsigned short* __restrict__ cidx,
                                 const float* __restrict__ dinv, const float* __restrict__ b,
                                 float* __restrict__ Y, int M) {
    constexpr int NC = 40;
    constexpr int NQ = 10;
    const int lane = threadIdx.x & 63;
    const int node = blockIdx.x * 4 + (threadIdx.x >> 6);
    if (node >= M) return;
    const int grp = lane >> 4;                 // 0..3
    const int sub = lane & 15;                 // 0..15
    const bool act = (sub < NQ);
    const int start = rowptr[node];
    const int cnt = deg[node];

    float a[4] = {0.f, 0.f, 0.f, 0.f};
    float c[4] = {0.f, 0.f, 0.f, 0.f};

    for (int base = 0; base < cnt; base += 64) {
        const int nthis = min(64, cnt - base);
        int myidx = (lane < nthis) ? (int)cidx[start + base + lane] : 0;
        int j = 0;
        for (; j + 8 <= nthis; j += 8) {
            int s0 = __shfl(myidx, j + grp, 64);
            int s1 = __shfl(myidx, j + 4 + grp, 64);
            if (act) {
                uint2 v0 = *(const uint2*)(G + (size_t)s0 * NC + sub * 4);
                uint2 v1 = *(const uint2*)(G + (size_t)s1 * NC + sub * 4);
                acc_bf16x4(v0, a);
                acc_bf16x4(v1, c);
            }
        }
        if (j + 4 <= nthis) {
            int s0 = __shfl(myidx, j + grp, 64);
            if (act) {
                uint2 v0 = *(const uint2*)(G + (size_t)s0 * NC + sub * 4);
                acc_bf16x4(v0, a);
            }
            j += 4;
        }
        const int rem = nthis - j;             // 0..3
        if (grp < rem) {
            int s0 = __shfl(myidx, j + grp, 64);
            if (act) {
                uint2 v0 = *(const uint2*)(G + (size_t)s0 * NC + sub * 4);
                acc_bf16x4(v0, c);
            }
        }
    }
#pragma unroll
    for (int k = 0; k < 4; ++k) a[k] += c[k];
#pragma unroll
    for (int k = 0; k < 4; ++k) {
        a[k] += __shfl_xor(a[k], 16, 64);
        a[k] += __shfl_xor(a[k], 32, 64);
    }
    float v[4];
    {
        float self[4] = {0.f, 0.f, 0.f, 0.f};
        float4 bb = make_float4(0.f, 0.f, 0.f, 0.f);
        if (act) {
            uint2 sv = *(const uint2*)(G + (size_t)node * NC + sub * 4);
            self[0] = bf2f((unsigned short)(sv.x & 0xffffu));
            self[1] = bf2f((unsigned short)(sv.x >> 16));
            self[2] = bf2f((unsigned short)(sv.y & 0xffffu));
            self[3] = bf2f((unsigned short)(sv.y >> 16));
            bb = *(const float4*)(b + sub * 4);
        }
        const float di = dinv[node];
        v[0] = fmaxf((a[0] + self[0]) * di + bb.x, 0.f);
        v[1] = fmaxf((a[1] + self[1]) * di + bb.y, 0.f);
        v[2] = fmaxf((a[2] + self[2]) * di + bb.z, 0.f);
        v[3] = fmaxf((a[3] + self[3]) * di + bb.w, 0.f);
    }
    float m = act ? fmaxf(fmaxf(v[0], v[1]), fmaxf(v[2], v[3])) : -INFINITY;
#pragma unroll
    for (int o = 1; o < 16; o <<= 1) m = fmaxf(m, __shfl_xor(m, o, 64));
    float es = act ? (expf(v[0] - m) + expf(v[1] - m) + expf(v[2] - m) + expf(v[3] - m)) : 0.f;
#pragma unroll
    for (int o = 1; o < 16; o <<= 1) es += __shfl_xor(es, o, 64);
    const float ls = logf(es);
    if (act && grp == 0) {
        *((float4*)(Y + (size_t)node * NC + sub * 4)) =
            make_float4(v[0] - m - ls, v[1] - m - ls, v[2] - m - ls, v[3] - m - ls);
    }
}

extern "C" void kernel_launch(void* const* d_in, const int* in_sizes, int n_in,
                              void* d_out, int out_size, void* d_ws, size_t ws_size,
                              hipStream_t stream) {
    const float* x  = (const float*)d_in[0];
    const int*   ei = (const int*)d_in[1];        // [2, E] int32
    const float* W1 = (const float*)d_in[2];
    const float* b1 = (const float*)d_in[3];
    const float* W2 = (const float*)d_in[4];
    const float* b2 = (const float*)d_in[5];
    const float* W3 = (const float*)d_in[6];
    const float* b3 = (const float*)d_in[7];
    float* out = (float*)d_out;

    const int M  = in_sizes[0] / DF;              // 50000
    const int E  = in_sizes[1] / 2;               // 800000
    (void)ws_size; (void)n_in; (void)out_size;

    const int* src = ei;
    const int* dst = ei + E;

    const size_t Ma = ((size_t)M + 63) & ~63ull;
    const size_t Ea = ((size_t)E + 63) & ~63ull;

    // workspace layout
    int* deg    = (int*)d_ws;                            // Ma
    int* rowptr = deg + Ma;                              // Ma
    int* cursor = rowptr + Ma;                           // Ma
    int* bsum   = cursor + Ma;                           // 256
    unsigned short* cidx = (unsigned short*)(bsum + 256);        // Ea (u16)
    float* dinv = (float*)(cidx + Ea);                   // Ma
    unsigned short* G0 = (unsigned short*)(dinv + Ma);           // Ma*64 (bf16)
    unsigned short* G1 = G0 + Ma * DF;                   // Ma*64 (bf16)

    const int gN = (M + TB - 1) / TB;
    const int nb = gN;                   // scan blocks (196 <= 256)
    const int psize = (M + NPART - 1) / NPART;
    const int partGrd = NPART * 96;      // 8 partitions x 96 slices

    // --- CSR build + dinv (once, reused by all 3 layers) ---
    zero_int_kernel<<<gN, TB, 0, stream>>>(deg, M);
    count_deg_part_kernel<<<partGrd, TB, 0, stream>>>(dst, deg, E, psize);
    scan_block_kernel<<<nb, TB, 0, stream>>>(deg, rowptr, bsum, dinv, M);
    add_offsets_kernel<<<nb, TB, 0, stream>>>(rowptr, bsum, cursor, M, nb);
    fill_csr_part_kernel<<<partGrd, TB, 0, stream>>>(src, dst, cursor, cidx, E, psize);

    const int nt      = (M + 15) / 16;            // 16-row tiles
    const int gemmGrd = (nt + 3) / 4;             // 4 waves/block
    const int aggGrd  = (M + 3) / 4;

    // --- layer 1 ---
    gemm_mfma_kernel<64, float><<<gemmGrd, TB, 0, stream>>>(x, W1, dinv, G0, M);
    agg64_kernel<<<aggGrd, TB, 0, stream>>>(G0, rowptr, deg, cidx, dinv, b1, G1, M);
    // --- layer 2 ---
    gemm_mfma_kernel<64, unsigned short><<<gemmGrd, TB, 0, stream>>>(G1, W2, dinv, G0, M);
    agg64_kernel<<<aggGrd, TB, 0, stream>>>(G0, rowptr, deg, cidx, dinv, b2, G1, M);
    // --- layer 3 (40 cols) + fused log_softmax ---
    gemm_mfma_kernel<40, unsigned short><<<gemmGrd, TB, 0, stream>>>(G1, W3, dinv, G0, M);
    agg40_lsm_kernel<<<aggGrd, TB, 0, stream>>>(G0, rowptr, deg, cidx, dinv, b3, out, M);
}

// Round 11
// 194.577 us; speedup vs baseline: 1.3597x; 1.0095x over previous
//
#include <hip/hip_runtime.h>
#include <math.h>

// ---------------------------------------------------------------------------
// GCN, atomic-free aggregation via per-call CSR (bucket by dst):
//   deg count (dst-partitioned) -> block scan(+dinv) -> add_offsets (fused
//   bsum scan) -> fill (dst-partitioned, XCD-local, u16)          [once]
//   gemm1 (MFMA 16x16x32 bf16, W frags in VGPRs, zero LDS): G1=(x@W1)*dinv
//   aggmm<64>: y1=relu(dinv*(G1self+gather)+b1) -> LDS[16][72] -> MFMA
//              G2=(Y1@W2)*dinv   [agg + next-layer GEMM fused per 16 nodes]
//   aggmm<40>: same with W3 -> G3
//   agg40_lsm: y3=relu(...b3); out=log_softmax(y3)
// Fusion design: block=4 waves=16 nodes. Each wave aggs 4 nodes (gather 8
// edge rows/instr via uint4, butterfly shfl_xor(8|16|32)), packs rows into
// padded LDS (stride 144B -> <=2-way bank alias, free), syncthreads, then
// each wave MFMAs its own 16-col tile (A frags from LDS rows, B frags from
// W in VGPRs — r10's verified layouts). NOT r9's per-node LDS gemv (256
// LDS-pipe ops/node, 74us). r7 lesson: keep occupancy, no big reg tiles.
// MFMA layouts (guide m89/m97): A lane(m=l&15,g=l>>4)=A[m][g*8+j];
//   B lane(n=l&15,g)=B[g*8+j][n]; C/D: col=l&15, row=(l>>4)*4+reg.
// cidx u16 (N_NODES=50000<65536).
// NOTE: no hipMemsetAsync — rocclr fillBuffer took 45.9us for 195KB in-graph.
// ---------------------------------------------------------------------------

#define DF 64
#define TB 256
#define NPART 8

typedef __attribute__((ext_vector_type(8))) short bf16x8;
typedef __attribute__((ext_vector_type(4))) float f32x4;

__device__ __forceinline__ unsigned short f2bf(float f) {
    union { float f; unsigned u; } c; c.f = f;
    unsigned u = c.u;
    return (unsigned short)((u + 0x7fffu + ((u >> 16) & 1u)) >> 16);   // RNE
}
__device__ __forceinline__ float bf2f(unsigned short h) {
    union { unsigned u; float f; } c; c.u = ((unsigned)h) << 16;
    return c.f;
}
__device__ __forceinline__ void acc_bf16x8(uint4 v, float* a) {
    a[0] += bf2f((unsigned short)(v.x & 0xffffu));
    a[1] += bf2f((unsigned short)(v.x >> 16));
    a[2] += bf2f((unsigned short)(v.y & 0xffffu));
    a[3] += bf2f((unsigned short)(v.y >> 16));
    a[4] += bf2f((unsigned short)(v.z & 0xffffu));
    a[5] += bf2f((unsigned short)(v.z >> 16));
    a[6] += bf2f((unsigned short)(v.w & 0xffffu));
    a[7] += bf2f((unsigned short)(v.w >> 16));
}
__device__ __forceinline__ void acc_bf16x4(uint2 v, float* a) {
    a[0] += bf2f((unsigned short)(v.x & 0xffffu));
    a[1] += bf2f((unsigned short)(v.x >> 16));
    a[2] += bf2f((unsigned short)(v.y & 0xffffu));
    a[3] += bf2f((unsigned short)(v.y >> 16));
}

__global__ void zero_int_kernel(int* __restrict__ p, int n) {
    int i = blockIdx.x * blockDim.x + threadIdx.x;
    if (i < n) p[i] = 0;
}

__global__ void count_deg_part_kernel(const int* __restrict__ dst, int* __restrict__ deg,
                                      int e, int psize) {
    const int p   = blockIdx.x & (NPART - 1);
    const int sl  = blockIdx.x / NPART;
    const int nsl = gridDim.x / NPART;
    const int lo = p * psize, hi = lo + psize;
    for (int i = sl * TB + threadIdx.x; i < e; i += nsl * TB) {
        int d = dst[i];
        if (d >= lo && d < hi) atomicAdd(&deg[d], 1);
    }
}

// per-block exclusive scan of deg -> ex (partial), block totals -> bsum; also dinv
__global__ void scan_block_kernel(const int* __restrict__ deg, int* __restrict__ ex,
                                  int* __restrict__ bsum, float* __restrict__ dinv, int n) {
    __shared__ int s[TB];
    const int t = threadIdx.x;
    const int i = blockIdx.x * TB + t;
    int v = (i < n) ? deg[i] : 0;
    if (i < n) dinv[i] = rsqrtf((float)(v + 1));   // +1 self-loop
    s[t] = v; __syncthreads();
#pragma unroll
    for (int o = 1; o < TB; o <<= 1) {
        int u = (t >= o) ? s[t - o] : 0;
        __syncthreads();
        s[t] += u;
        __syncthreads();
    }
    if (i < n) ex[i] = s[t] - v;
    if (t == TB - 1) bsum[blockIdx.x] = s[TB - 1];
}

// each block redundantly scans bsum (nb <= 256) in LDS, then offsets its slice
__global__ void add_offsets_kernel(int* __restrict__ ex, const int* __restrict__ bsum,
                                   int* __restrict__ cursor, int n, int nb) {
    __shared__ int s[TB];
    const int t = threadIdx.x;
    int v = (t < nb) ? bsum[t] : 0;
    s[t] = v; __syncthreads();
#pragma unroll
    for (int o = 1; o < TB; o <<= 1) {
        int u = (t >= o) ? s[t - o] : 0;
        __syncthreads();
        s[t] += u;
        __syncthreads();
    }
    const int boff = (blockIdx.x > 0) ? s[blockIdx.x - 1] : 0;
    const int i = blockIdx.x * TB + t;
    if (i < n) {
        int r = ex[i] + boff;
        ex[i] = r;
        cursor[i] = r;
    }
}

__global__ void fill_csr_part_kernel(const int* __restrict__ src, const int* __restrict__ dst,
                                     int* __restrict__ cursor,
                                     unsigned short* __restrict__ cidx, int e, int psize) {
    const int p   = blockIdx.x & (NPART - 1);
    const int sl  = blockIdx.x / NPART;
    const int nsl = gridDim.x / NPART;
    const int lo = p * psize, hi = lo + psize;
    for (int i = sl * TB + threadIdx.x; i < e; i += nsl * TB) {
        int d = dst[i];
        if (d >= lo && d < hi) {
            int pos = atomicAdd(&cursor[d], 1);
            cidx[pos] = (unsigned short)src[i];
        }
    }
}

// G[M x 64](bf16) = (X[M x 64] @ W1[64 x 64]) * dinv[row], via MFMA. Layer 1.
__global__ __launch_bounds__(256) void gemm_mfma_kernel(
        const float* __restrict__ X, const float* __restrict__ W,
        const float* __restrict__ dinv, unsigned short* __restrict__ G, int M) {
    const int lane = threadIdx.x & 63;
    const int wid  = threadIdx.x >> 6;         // 0..3
    const int t    = blockIdx.x * 4 + wid;     // row-tile index
    const int nt   = (M + 15) >> 4;
    if (t >= nt) return;
    const int n = lane & 15;
    const int g = lane >> 4;

    bf16x8 bf[4][2];
#pragma unroll
    for (int ct = 0; ct < 4; ++ct) {
        const int c = ct * 16 + n;
#pragma unroll
        for (int ks = 0; ks < 2; ++ks)
#pragma unroll
            for (int j = 0; j < 8; ++j)
                bf[ct][ks][j] = (short)f2bf(W[(ks * 32 + g * 8 + j) * 64 + c]);
    }

    const int row_a = t * 16 + n;
    const int ra = (row_a < M) ? row_a : (M - 1);
    bf16x8 af[2];
#pragma unroll
    for (int ks = 0; ks < 2; ++ks) {
        float4 p0 = *(const float4*)(X + (size_t)ra * 64 + ks * 32 + g * 8);
        float4 p1 = *(const float4*)(X + (size_t)ra * 64 + ks * 32 + g * 8 + 4);
        af[ks][0] = (short)f2bf(p0.x); af[ks][1] = (short)f2bf(p0.y);
        af[ks][2] = (short)f2bf(p0.z); af[ks][3] = (short)f2bf(p0.w);
        af[ks][4] = (short)f2bf(p1.x); af[ks][5] = (short)f2bf(p1.y);
        af[ks][6] = (short)f2bf(p1.z); af[ks][7] = (short)f2bf(p1.w);
    }

    const int rbase = t * 16 + g * 4;
    float di[4];
#pragma unroll
    for (int r = 0; r < 4; ++r) {
        int rr = rbase + r;
        di[r] = dinv[(rr < M) ? rr : (M - 1)];
    }

#pragma unroll
    for (int ct = 0; ct < 4; ++ct) {
        f32x4 acc = {0.f, 0.f, 0.f, 0.f};
        acc = __builtin_amdgcn_mfma_f32_16x16x32_bf16(af[0], bf[ct][0], acc, 0, 0, 0);
        acc = __builtin_amdgcn_mfma_f32_16x16x32_bf16(af[1], bf[ct][1], acc, 0, 0, 0);
        const int col = ct * 16 + n;
#pragma unroll
        for (int r = 0; r < 4; ++r) {
            const int row = rbase + r;
            if (row < M)
                G[(size_t)row * 64 + col] = f2bf(acc[r] * di[r]);
        }
    }
}

// Fused: aggregate 16 nodes (4 per wave) + next-layer MFMA GEMM.
// Gout[16 x NCO] = (relu(dinv*(self+gather)+b)[16 x 64] @ Wn[64 x NCO]) * dinv
template <int NCO>
__global__ __launch_bounds__(256) void aggmm_kernel(
        const unsigned short* __restrict__ G,
        const int* __restrict__ rowptr, const int* __restrict__ deg,
        const unsigned short* __restrict__ cidx,
        const float* __restrict__ dinv, const float* __restrict__ b,
        const float* __restrict__ Wn,
        unsigned short* __restrict__ Gout, int M) {
    __shared__ unsigned short Ys[16][72];      // +8 pad: stride 144B, 2-way max
    __shared__ float ds[16];
    const int tid  = threadIdx.x;
    const int lane = tid & 63;
    const int wid  = tid >> 6;                 // 0..3
    const int base = blockIdx.x * 16;
    const int grp = lane >> 3;                 // 0..7 edge slot
    const int sub = lane & 7;                  // 0..7 col octet
    const int n16 = lane & 15;
    const int g16 = lane >> 4;

    // B fragments for this wave's col-tile ct = wid (issued early)
    const bool wactive = (wid * 16 < NCO);
    bf16x8 bf[2];
    if (wactive) {
        const int c = wid * 16 + n16;
#pragma unroll
        for (int ks = 0; ks < 2; ++ks)
#pragma unroll
            for (int j = 0; j < 8; ++j) {
                const int k = ks * 32 + g16 * 8 + j;
                float w = (c < NCO) ? Wn[k * NCO + c] : 0.f;
                bf[ks][j] = (short)f2bf(w);
            }
    }

    // agg phase: wave wid owns rows wid*4 .. wid*4+3
    for (int i = 0; i < 4; ++i) {
        const int nrow  = wid * 4 + i;
        const int node0 = base + nrow;
        const int node  = (node0 < M) ? node0 : (M - 1);   // clamped: safe garbage
        const int start = rowptr[node];
        const int cnt   = deg[node];

        float a[8] = {0.f, 0.f, 0.f, 0.f, 0.f, 0.f, 0.f, 0.f};
        float c8[8] = {0.f, 0.f, 0.f, 0.f, 0.f, 0.f, 0.f, 0.f};
        for (int bs = 0; bs < cnt; bs += 64) {
            const int nthis = min(64, cnt - bs);
            int myidx = (lane < nthis) ? (int)cidx[start + bs + lane] : 0;
            int j = 0;
            for (; j + 16 <= nthis; j += 16) {
                int s0 = __shfl(myidx, j + grp, 64);
                int s1 = __shfl(myidx, j + 8 + grp, 64);
                uint4 v0 = *(const uint4*)(G + (size_t)s0 * 64 + sub * 8);
                uint4 v1 = *(const uint4*)(G + (size_t)s1 * 64 + sub * 8);
                acc_bf16x8(v0, a);
                acc_bf16x8(v1, c8);
            }
            if (j + 8 <= nthis) {
                int s0 = __shfl(myidx, j + grp, 64);
                uint4 v0 = *(const uint4*)(G + (size_t)s0 * 64 + sub * 8);
                acc_bf16x8(v0, a);
                j += 8;
            }
            const int rem = nthis - j;
            if (grp < rem) {
                int s0 = __shfl(myidx, j + grp, 64);
                uint4 v0 = *(const uint4*)(G + (size_t)s0 * 64 + sub * 8);
                acc_bf16x8(v0, c8);
            }
        }
#pragma unroll
        for (int k = 0; k < 8; ++k) a[k] += c8[k];
#pragma unroll
        for (int k = 0; k < 8; ++k) {
            a[k] += __shfl_xor(a[k], 8, 64);
            a[k] += __shfl_xor(a[k], 16, 64);
            a[k] += __shfl_xor(a[k], 32, 64);
        }
        if (grp == 0) {
            uint4 sv = *(const uint4*)(G + (size_t)node * 64 + sub * 8);
            float4 b0 = *(const float4*)(b + sub * 8);
            float4 b1 = *(const float4*)(b + sub * 8 + 4);
            const float di = dinv[node];
            float v[8];
            v[0] = fmaxf((a[0] + bf2f((unsigned short)(sv.x & 0xffffu))) * di + b0.x, 0.f);
            v[1] = fmaxf((a[1] + bf2f((unsigned short)(sv.x >> 16)))     * di + b0.y, 0.f);
            v[2] = fmaxf((a[2] + bf2f((unsigned short)(sv.y & 0xffffu))) * di + b0.z, 0.f);
            v[3] = fmaxf((a[3] + bf2f((unsigned short)(sv.y >> 16)))     * di + b0.w, 0.f);
            v[4] = fmaxf((a[4] + bf2f((unsigned short)(sv.z & 0xffffu))) * di + b1.x, 0.f);
            v[5] = fmaxf((a[5] + bf2f((unsigned short)(sv.z >> 16)))     * di + b1.y, 0.f);
            v[6] = fmaxf((a[6] + bf2f((unsigned short)(sv.w & 0xffffu))) * di + b1.z, 0.f);
            v[7] = fmaxf((a[7] + bf2f((unsigned short)(sv.w >> 16)))     * di + b1.w, 0.f);
            uint4 o;
            o.x = (unsigned)f2bf(v[0]) | ((unsigned)f2bf(v[1]) << 16);
            o.y = (unsigned)f2bf(v[2]) | ((unsigned)f2bf(v[3]) << 16);
            o.z = (unsigned)f2bf(v[4]) | ((unsigned)f2bf(v[5]) << 16);
            o.w = (unsigned)f2bf(v[6]) | ((unsigned)f2bf(v[7]) << 16);
            *((uint4*)&Ys[nrow][sub * 8]) = o;
            if (sub == 0) ds[nrow] = di;
        }
    }
    __syncthreads();

    // MFMA phase: wave wid -> col tile [wid*16, wid*16+16)
    if (!wactive) return;
    bf16x8 af[2];
#pragma unroll
    for (int ks = 0; ks < 2; ++ks)
        af[ks] = *(const bf16x8*)&Ys[n16][ks * 32 + g16 * 8];
    f32x4 acc = {0.f, 0.f, 0.f, 0.f};
    acc = __builtin_amdgcn_mfma_f32_16x16x32_bf16(af[0], bf[0], acc, 0, 0, 0);
    acc = __builtin_amdgcn_mfma_f32_16x16x32_bf16(af[1], bf[1], acc, 0, 0, 0);
    const int col = wid * 16 + n16;
#pragma unroll
    for (int r = 0; r < 4; ++r) {
        const int row = base + g16 * 4 + r;
        if (row < M && col < NCO)
            Gout[(size_t)row * NCO + col] = f2bf(acc[r] * ds[g16 * 4 + r]);
    }
}

// NC=40 aggregation + fused log_softmax. lane = grp(2b)*16 + sub(4b);
// lane owns cols [sub*4, sub*4+4); 4 edge rows per instruction.
__global__ void agg40_lsm_kernel(const unsigned short* __restrict__ G,
                                 const int* __restrict__ rowptr, const int* __restrict__ deg,
                                 const unsigned short* __restrict__ cidx,
                                 const float* __restrict__ dinv, const float* __restrict__ b,
                                 float* __restrict__ Y, int M) {
    constexpr int NC = 40;
    constexpr int NQ = 10;
    const int lane = threadIdx.x & 63;
    const int node = blockIdx.x * 4 + (threadIdx.x >> 6);
    if (node >= M) return;
    const int grp = lane >> 4;                 // 0..3
    const int sub = lane & 15;                 // 0..15
    const bool act = (sub < NQ);
    const int start = rowptr[node];
    const int cnt = deg[node];

    float a[4] = {0.f, 0.f, 0.f, 0.f};
    float c[4] = {0.f, 0.f, 0.f, 0.f};

    for (int base = 0; base < cnt; base += 64) {
        const int nthis = min(64, cnt - base);
        int myidx = (lane < nthis) ? (int)cidx[start + base + lane] : 0;
        int j = 0;
        for (; j + 8 <= nthis; j += 8) {
            int s0 = __shfl(myidx, j + grp, 64);
            int s1 = __shfl(myidx, j + 4 + grp, 64);
            if (act) {
                uint2 v0 = *(const uint2*)(G + (size_t)s0 * NC + sub * 4);
                uint2 v1 = *(const uint2*)(G + (size_t)s1 * NC + sub * 4);
                acc_bf16x4(v0, a);
                acc_bf16x4(v1, c);
            }
        }
        if (j + 4 <= nthis) {
            int s0 = __shfl(myidx, j + grp, 64);
            if (act) {
                uint2 v0 = *(const uint2*)(G + (size_t)s0 * NC + sub * 4);
                acc_bf16x4(v0, a);
            }
            j += 4;
        }
        const int rem = nthis - j;             // 0..3
        if (grp < rem) {
            int s0 = __shfl(myidx, j + grp, 64);
            if (act) {
                uint2 v0 = *(const uint2*)(G + (size_t)s0 * NC + sub * 4);
                acc_bf16x4(v0, c);
            }
        }
    }
#pragma unroll
    for (int k = 0; k < 4; ++k) a[k] += c[k];
#pragma unroll
    for (int k = 0; k < 4; ++k) {
        a[k] += __shfl_xor(a[k], 16, 64);
        a[k] += __shfl_xor(a[k], 32, 64);
    }
    float v[4];
    {
        float self[4] = {0.f, 0.f, 0.f, 0.f};
        float4 bb = make_float4(0.f, 0.f, 0.f, 0.f);
        if (act) {
            uint2 sv = *(const uint2*)(G + (size_t)node * NC + sub * 4);
            self[0] = bf2f((unsigned short)(sv.x & 0xffffu));
            self[1] = bf2f((unsigned short)(sv.x >> 16));
            self[2] = bf2f((unsigned short)(sv.y & 0xffffu));
            self[3] = bf2f((unsigned short)(sv.y >> 16));
            bb = *(const float4*)(b + sub * 4);
        }
        const float di = dinv[node];
        v[0] = fmaxf((a[0] + self[0]) * di + bb.x, 0.f);
        v[1] = fmaxf((a[1] + self[1]) * di + bb.y, 0.f);
        v[2] = fmaxf((a[2] + self[2]) * di + bb.z, 0.f);
        v[3] = fmaxf((a[3] + self[3]) * di + bb.w, 0.f);
    }
    float m = act ? fmaxf(fmaxf(v[0], v[1]), fmaxf(v[2], v[3])) : -INFINITY;
#pragma unroll
    for (int o = 1; o < 16; o <<= 1) m = fmaxf(m, __shfl_xor(m, o, 64));
    float es = act ? (expf(v[0] - m) + expf(v[1] - m) + expf(v[2] - m) + expf(v[3] - m)) : 0.f;
#pragma unroll
    for (int o = 1; o < 16; o <<= 1) es += __shfl_xor(es, o, 64);
    const float ls = logf(es);
    if (act && grp == 0) {
        *((float4*)(Y + (size_t)node * NC + sub * 4)) =
            make_float4(v[0] - m - ls, v[1] - m - ls, v[2] - m - ls, v[3] - m - ls);
    }
}

extern "C" void kernel_launch(void* const* d_in, const int* in_sizes, int n_in,
                              void* d_out, int out_size, void* d_ws, size_t ws_size,
                              hipStream_t stream) {
    const float* x  = (const float*)d_in[0];
    const int*   ei = (const int*)d_in[1];        // [2, E] int32
    const float* W1 = (const float*)d_in[2];
    const float* b1 = (const float*)d_in[3];
    const float* W2 = (const float*)d_in[4];
    const float* b2 = (const float*)d_in[5];
    const float* W3 = (const float*)d_in[6];
    const float* b3 = (const float*)d_in[7];
    float* out = (float*)d_out;

    const int M  = in_sizes[0] / DF;              // 50000
    const int E  = in_sizes[1] / 2;               // 800000
    (void)ws_size; (void)n_in; (void)out_size;

    const int* src = ei;
    const int* dst = ei + E;

    const size_t Ma = ((size_t)M + 63) & ~63ull;
    const size_t Ea = ((size_t)E + 63) & ~63ull;

    // workspace layout
    int* deg    = (int*)d_ws;                            // Ma
    int* rowptr = deg + Ma;                              // Ma
    int* cursor = rowptr + Ma;                           // Ma
    int* bsum   = cursor + Ma;                           // 256
    unsigned short* cidx = (unsigned short*)(bsum + 256);        // Ea (u16)
    float* dinv = (float*)(cidx + Ea);                   // Ma
    unsigned short* G0 = (unsigned short*)(dinv + Ma);           // Ma*64 (bf16)
    unsigned short* G1 = G0 + Ma * DF;                   // Ma*64 (bf16)

    const int gN = (M + TB - 1) / TB;
    const int nb = gN;                   // scan blocks (196 <= 256)
    const int psize = (M + NPART - 1) / NPART;
    const int partGrd = NPART * 96;      // 8 partitions x 96 slices

    // --- CSR build + dinv (once, reused by all 3 layers) ---
    zero_int_kernel<<<gN, TB, 0, stream>>>(deg, M);
    count_deg_part_kernel<<<partGrd, TB, 0, stream>>>(dst, deg, E, psize);
    scan_block_kernel<<<nb, TB, 0, stream>>>(deg, rowptr, bsum, dinv, M);
    add_offsets_kernel<<<nb, TB, 0, stream>>>(rowptr, bsum, cursor, M, nb);
    fill_csr_part_kernel<<<partGrd, TB, 0, stream>>>(src, dst, cursor, cidx, E, psize);

    const int nt      = (M + 15) / 16;            // 16-row tiles
    const int gemmGrd = (nt + 3) / 4;             // 4 waves/block (layer-1 gemm)
    const int fusGrd  = nt;                       // 16 nodes/block (fused)
    const int aggGrd  = (M + 3) / 4;

    // layer-1 dense transform
    gemm_mfma_kernel<<<gemmGrd, TB, 0, stream>>>(x, W1, dinv, G0, M);
    // layer-1 aggregate + layer-2 GEMM (fused)
    aggmm_kernel<64><<<fusGrd, TB, 0, stream>>>(G0, rowptr, deg, cidx, dinv, b1, W2, G1, M);
    // layer-2 aggregate + layer-3 GEMM (fused)
    aggmm_kernel<40><<<fusGrd, TB, 0, stream>>>(G1, rowptr, deg, cidx, dinv, b2, W3, G0, M);
    // layer-3 aggregate + log_softmax
    agg40_lsm_kernel<<<aggGrd, TB, 0, stream>>>(G0, rowptr, deg, cidx, dinv, b3, out, M);
}